// Round 5
// baseline (11668.521 us; speedup 1.0000x reference)
//
#include <hip/hip_runtime.h>
#include <math.h>

#define BLOCK 256
#define PB 128  // pairs (problems) per block

// prep: W0 [27][128] -> W0p [32][128] (zero rows); W4 [128][25] -> W4p [128][32]
// (zero cols); b4 [25] -> b4p [32]
__global__ void prep_kernel(const float* __restrict__ W0, const float* __restrict__ W4,
                            const float* __restrict__ b4, float* __restrict__ W0p,
                            float* __restrict__ W4p, float* __restrict__ b4p) {
    const int t = blockIdx.x * blockDim.x + threadIdx.x;
    if (t < 32 * 128) {
        const int k = t >> 7, j = t & 127;
        W0p[t] = (k < 27) ? W0[k * 128 + j] : 0.0f;
    }
    if (t < 128 * 32) {
        const int k = t >> 5, j = t & 31;
        W4p[t] = (j < 25) ? W4[k * 25 + j] : 0.0f;
    }
    if (t < 32) b4p[t] = (t < 25) ? b4[t] : 0.0f;
}

// NOUT-output GEMM slice over NROWS rows; 2-row double-buffered batches.
// W points at (row0, my NOUT cols); row stride WSTRIDE; h at hP[r*PB].
template <int NROWS, int WSTRIDE, int NOUT>
__device__ __forceinline__ void gemmN(const float* __restrict__ W,
                                      const float* __restrict__ hP,
                                      float* __restrict__ oc) {
    constexpr int NB = NROWS / 2;  // number of 2-row batches
    constexpr int Q = NOUT / 4;
    static_assert(NROWS % 4 == 0, "NB must be even");
    float4 A[2 * Q], Bf[2 * Q];
    float hA[2], hB[2];
    // prologue: batch 0 -> A
#pragma unroll
    for (int r = 0; r < 2; ++r) {
#pragma unroll
        for (int q = 0; q < Q; ++q)
            A[r * Q + q] = *(const float4*)(W + r * WSTRIDE + q * 4);
        hA[r] = hP[r * PB];
    }
    for (int b = 0; b < NB; b += 2) {
        // issue batch b+1 -> Bf
        {
            const float* Wb = W + (b + 1) * 2 * WSTRIDE;
            const float* hb = hP + (b + 1) * 2 * PB;
#pragma unroll
            for (int r = 0; r < 2; ++r) {
#pragma unroll
                for (int q = 0; q < Q; ++q)
                    Bf[r * Q + q] = *(const float4*)(Wb + r * WSTRIDE + q * 4);
                hB[r] = hb[r * PB];
            }
        }
        // FMA batch A (rows 2b, 2b+1)
#pragma unroll
        for (int r = 0; r < 2; ++r) {
            const float h = hA[r];
#pragma unroll
            for (int q = 0; q < Q; ++q) {
                const float4 w = A[r * Q + q];
                oc[q * 4 + 0] = fmaf(h, w.x, oc[q * 4 + 0]);
                oc[q * 4 + 1] = fmaf(h, w.y, oc[q * 4 + 1]);
                oc[q * 4 + 2] = fmaf(h, w.z, oc[q * 4 + 2]);
                oc[q * 4 + 3] = fmaf(h, w.w, oc[q * 4 + 3]);
            }
        }
        // issue batch b+2 -> A (clamped redundant reload at the end)
        {
            const int bn = (b + 2 < NB) ? (b + 2) : (NB - 2);
            const float* Wa = W + bn * 2 * WSTRIDE;
            const float* ha = hP + bn * 2 * PB;
#pragma unroll
            for (int r = 0; r < 2; ++r) {
#pragma unroll
                for (int q = 0; q < Q; ++q)
                    A[r * Q + q] = *(const float4*)(Wa + r * WSTRIDE + q * 4);
                hA[r] = ha[r * PB];
            }
        }
        // FMA batch Bf
#pragma unroll
        for (int r = 0; r < 2; ++r) {
            const float h = hB[r];
#pragma unroll
            for (int q = 0; q < Q; ++q) {
                const float4 w = Bf[r * Q + q];
                oc[q * 4 + 0] = fmaf(h, w.x, oc[q * 4 + 0]);
                oc[q * 4 + 1] = fmaf(h, w.y, oc[q * 4 + 1]);
                oc[q * 4 + 2] = fmaf(h, w.z, oc[q * 4 + 2]);
                oc[q * 4 + 3] = fmaf(h, w.w, oc[q * 4 + 3]);
            }
        }
    }
}

// full 64-output layer for my half: 2 chunks of 32 outputs
template <int NROWS, int WSTRIDE>
__device__ __forceinline__ void layer64(const float* __restrict__ W,
                                        const float* __restrict__ bia,
                                        const float* __restrict__ hP,
                                        const int soff,  // s*64
                                        float* __restrict__ o) {
#pragma unroll
    for (int jq = 0; jq < 2; ++jq) {
        float* __restrict__ oc = o + jq * 32;
        const float* bp = bia + soff + jq * 32;
#pragma unroll
        for (int q = 0; q < 8; ++q) {
            const float4 bb = *(const float4*)(bp + q * 4);
            oc[q * 4 + 0] = bb.x;
            oc[q * 4 + 1] = bb.y;
            oc[q * 4 + 2] = bb.z;
            oc[q * 4 + 3] = bb.w;
        }
        gemmN<NROWS, WSTRIDE, 32>(W + soff + jq * 32, hP, oc);
    }
}

__global__ __launch_bounds__(BLOCK)
__attribute__((amdgpu_waves_per_eu(2, 2))) void snarf_kernel(
    const float* __restrict__ xin, const float* __restrict__ bone_pts,
    const float* __restrict__ transforms, const float* __restrict__ delta_tf,
    const float* __restrict__ W0p, const float* __restrict__ b0,
    const float* __restrict__ W1, const float* __restrict__ b1,
    const float* __restrict__ W2, const float* __restrict__ b2,
    const float* __restrict__ W3, const float* __restrict__ b3,
    const float* __restrict__ W4p, const float* __restrict__ b4p,
    float* __restrict__ out, int Npts) {
    __shared__ float hL[128 * PB];  // 64 KiB, h[k][pair]
    const int tid = threadIdx.x;
    const int lane = tid & 63;
    const int s = (lane >> 5) & 1;                   // my half of the pair
    const int pair = (tid >> 6) * 32 + (lane & 31);  // 0..127
    const int M = Npts * 6;
    const int m = blockIdx.x * PB + pair;
    if (m >= M) return;
    const int n = m / 6;
    const int i = m - n * 6;

    float* __restrict__ hP = &hL[pair];
    float* __restrict__ hS = hP + s * 64 * PB;  // my h-write region
    const int soff = s * 64;

    // zero h rows 27..31 once (layer0 reads 32 rows; W0p rows 27..31 are zero)
    for (int r = 27 + s; r < 32; r += 2) hP[r * PB] = 0.0f;

    const float tx = xin[n * 3 + 0], ty = xin[n * 3 + 1], tz = xin[n * 3 + 2];

    // ---- init candidate: i<5 -> i-th nearest bone's delta transform; i==5 -> identity
    float xk0, xk1, xk2;
    if (i < 5) {
        float dprev = -1.0f;
        int jprev = -1;
        for (int r = 0; r <= i; ++r) {
            float bd = 3.4028235e38f;
            int bj = 0;
            for (int j = 0; j < 24; ++j) {
                const float ax = tx - bone_pts[j * 3 + 0];
                const float ay = ty - bone_pts[j * 3 + 1];
                const float az = tz - bone_pts[j * 3 + 2];
                const float d = sqrtf(ax * ax + ay * ay + az * az);
                const bool taken = (d < dprev) || (d == dprev && j <= jprev);
                if (!taken && d < bd) { bd = d; bj = j; }
            }
            dprev = bd;
            jprev = bj;
        }
        const float* T = delta_tf + jprev * 16;
        xk0 = fmaf(T[0], tx, fmaf(T[1], ty, fmaf(T[2], tz, T[3])));
        xk1 = fmaf(T[4], tx, fmaf(T[5], ty, fmaf(T[6], tz, T[7])));
        xk2 = fmaf(T[8], tx, fmaf(T[9], ty, fmaf(T[10], tz, T[11])));
    } else {
        xk0 = tx; xk1 = ty; xk2 = tz;
    }

    // ---- Broyden state (duplicated per pair lane; bitwise identical)
    float gx0 = 0.f, gx1 = 0.f, gx2 = 0.f;
    float J00 = 1.f, J01 = 0.f, J02 = 0.f;
    float J10 = 0.f, J11 = 1.f, J12 = 0.f;
    float J20 = 0.f, J21 = 0.f, J22 = 1.f;
    float up0 = 0.f, up1 = 0.f, up2 = 0.f;
    float xo0 = xk0, xo1 = xk1, xo2 = xk2;
    float nopt = 0.f;
    float dx0 = 0.f, dx1 = 0.f, dx2 = 0.f;
    float dg0 = 0.f, dg1 = 0.f, dg2 = 0.f;
    bool mask = true;

    float o[64];

    int step = -1;  // -1 init eval, 0..7 Broyden, 8 final eval
    while (step <= 8) {
        bool m3 = mask;
        if (step >= 0 && step < 8) {
            if (__ballot(mask) == 0ull) { step = 8; continue; }
            if (m3) {
                dx0 = up0; dx1 = up1; dx2 = up2;
                xk0 += dx0; xk1 += dx1; xk2 += dx2;
            }
        }
        float cx0 = xk0, cx1 = xk1, cx2 = xk2;
        if (step == 8) { cx0 = xo0; cx1 = xo1; cx2 = xo2; }

        // ---- positional encoding (both lanes compute all 27; each writes its half)
        float pe[27];
        pe[0] = cx0; pe[1] = cx1; pe[2] = cx2;
#pragma unroll
        for (int sc = 0; sc < 4; ++sc) {
            const float f = (float)(1 << sc);
            float s0, c0, s1, c1, s2, c2;
            sincosf(f * cx0, &s0, &c0);
            sincosf(f * cx1, &s1, &c1);
            sincosf(f * cx2, &s2, &c2);
            pe[3 + sc * 3 + 0] = s0;
            pe[3 + sc * 3 + 1] = s1;
            pe[3 + sc * 3 + 2] = s2;
            pe[15 + sc * 3 + 0] = c0;
            pe[15 + sc * 3 + 1] = c1;
            pe[15 + sc * 3 + 2] = c2;
        }
        if (s == 0) {
#pragma unroll
            for (int j = 0; j < 14; ++j) hP[j * PB] = pe[j];
        } else {
#pragma unroll
            for (int j = 14; j < 27; ++j) hP[j * PB] = pe[j];
        }

        layer64<32, 128>(W0p, b0, hP, soff, o);
#pragma unroll
        for (int k = 0; k < 64; ++k) hS[k * PB] = fmaxf(o[k], 0.0f);
        layer64<128, 128>(W1, b1, hP, soff, o);
#pragma unroll
        for (int k = 0; k < 64; ++k) hS[k * PB] = fmaxf(o[k], 0.0f);
        layer64<128, 128>(W2, b2, hP, soff, o);
#pragma unroll
        for (int k = 0; k < 64; ++k) hS[k * PB] = fmaxf(o[k], 0.0f);
        layer64<128, 128>(W3, b3, hP, soff, o);
#pragma unroll
        for (int k = 0; k < 64; ++k) hS[k * PB] = fmaxf(o[k], 0.0f);

        // ---- output layer: my 16 of 32 padded logits
        float lg[16];
        {
            const float* bp = b4p + s * 16;
#pragma unroll
            for (int q = 0; q < 4; ++q) {
                const float4 bb = *(const float4*)(bp + q * 4);
                lg[q * 4 + 0] = bb.x;
                lg[q * 4 + 1] = bb.y;
                lg[q * 4 + 2] = bb.z;
                lg[q * 4 + 3] = bb.w;
            }
        }
        gemmN<128, 32, 16>(W4p + s * 16, hP, lg);

        // exchange logits through LDS rows 0..31 (h fully consumed)
        {
            float* hW = hP + s * 16 * PB;
#pragma unroll
            for (int j = 0; j < 16; ++j) hW[j * PB] = lg[j];
        }
        float l25[25];
#pragma unroll
        for (int j = 0; j < 25; ++j) l25[j] = hP[j * PB];

        // softmax(5 * logits) over 25 (duplicated, identical)
        float zm = -3.4028235e38f;
#pragma unroll
        for (int j = 0; j < 25; ++j) {
            l25[j] = 5.0f * l25[j];
            zm = fmaxf(zm, l25[j]);
        }
        float ssum = 0.f;
#pragma unroll
        for (int j = 0; j < 25; ++j) {
            l25[j] = expf(l25[j] - zm);
            ssum += l25[j];
        }
        const float inv = 1.0f / ssum;

        float tf[12];
#pragma unroll
        for (int r = 0; r < 12; ++r) tf[r] = 0.f;
#pragma unroll
        for (int j = 0; j < 24; ++j) {
            const float wj = l25[j] * inv;
            const float* T = transforms + j * 16;
#pragma unroll
            for (int r = 0; r < 12; ++r) tf[r] = fmaf(wj, T[r], tf[r]);
        }
        {
            const float wj = l25[24] * inv;  // identity transform
            tf[0] += wj; tf[5] += wj; tf[10] += wj;
        }
        const float r0 = fmaf(tf[0], cx0, fmaf(tf[1], cx1, fmaf(tf[2], cx2, tf[3])));
        const float r1 = fmaf(tf[4], cx0, fmaf(tf[5], cx1, fmaf(tf[6], cx2, tf[7])));
        const float r2 = fmaf(tf[8], cx0, fmaf(tf[9], cx1, fmaf(tf[10], cx2, tf[11])));

        if (step == 8) {
            if (s == 0) {
                out[(size_t)m * 3 + 0] = r0;
                out[(size_t)m * 3 + 1] = r1;
                out[(size_t)m * 3 + 2] = r2;
                float* xopt_out = out + (size_t)M * 3;
                xopt_out[(size_t)m * 3 + 0] = xo0;
                xopt_out[(size_t)m * 3 + 1] = xo1;
                xopt_out[(size_t)m * 3 + 2] = xo2;
                out[(size_t)M * 6 + m] = nopt;
                out[(size_t)M * 7 + m] = (nopt < 1e-5f) ? 1.0f : 0.0f;
            }
            break;
        }

        const float g0 = r0 - tx, g1 = r1 - ty, g2 = r2 - tz;

        if (step == -1) {
            gx0 = g0; gx1 = g1; gx2 = g2;
            const float gn = sqrtf(g0 * g0 + g1 * g1 + g2 * g2);
            nopt = gn;
            up0 = -g0; up1 = -g1; up2 = -g2;  // Jinv = I
        } else {
            if (m3) {
                dg0 = g0 - gx0; dg1 = g1 - gx1; dg2 = g2 - gx2;
                gx0 += dg0; gx1 += dg1; gx2 += dg2;
            }
            const float gn = sqrtf(gx0 * gx0 + gx1 * gx1 + gx2 * gx2);
            const bool better = gn < nopt;
            if (better) {
                nopt = gn;
                xo0 = xk0; xo1 = xk1; xo2 = xk2;
            }
            mask = (nopt > 1e-5f) && (gn < 1.0f);

            const float v0 = dx0 * J00 + dx1 * J10 + dx2 * J20;
            const float v1 = dx0 * J01 + dx1 * J11 + dx2 * J21;
            const float v2 = dx0 * J02 + dx1 * J12 + dx2 * J22;
            const float Jd0 = J00 * dg0 + J01 * dg1 + J02 * dg2;
            const float Jd1 = J10 * dg0 + J11 * dg1 + J12 * dg2;
            const float Jd2 = J20 * dg0 + J21 * dg1 + J22 * dg2;
            const float a0 = dx0 - Jd0, a1 = dx1 - Jd1, a2 = dx2 - Jd2;
            float bden = v0 * dg0 + v1 * dg1 + v2 * dg2;
            bden += (bden >= 0.f) ? 1e-6f : -1e-6f;
            if (mask) {
                const float q0 = a0 / bden, q1 = a1 / bden, q2 = a2 / bden;
                J00 = fmaf(q0, v0, J00); J01 = fmaf(q0, v1, J01); J02 = fmaf(q0, v2, J02);
                J10 = fmaf(q1, v0, J10); J11 = fmaf(q1, v1, J11); J12 = fmaf(q1, v2, J12);
                J20 = fmaf(q2, v0, J20); J21 = fmaf(q2, v1, J21); J22 = fmaf(q2, v2, J22);
            }
            if (m3) {
                up0 = -(J00 * gx0 + J01 * gx1 + J02 * gx2);
                up1 = -(J10 * gx0 + J11 * gx1 + J12 * gx2);
                up2 = -(J20 * gx0 + J21 * gx1 + J22 * gx2);
            }
        }
        ++step;
    }
}

extern "C" void kernel_launch(void* const* d_in, const int* in_sizes, int n_in,
                              void* d_out, int out_size, void* d_ws, size_t ws_size,
                              hipStream_t stream) {
    const float* x = (const float*)d_in[0];
    const float* bone_pts = (const float*)d_in[1];
    const float* transforms = (const float*)d_in[2];
    const float* delta_tf = (const float*)d_in[3];
    const float* W0 = (const float*)d_in[4];
    const float* b0 = (const float*)d_in[5];
    const float* W1 = (const float*)d_in[6];
    const float* b1 = (const float*)d_in[7];
    const float* W2 = (const float*)d_in[8];
    const float* b2 = (const float*)d_in[9];
    const float* W3 = (const float*)d_in[10];
    const float* b3 = (const float*)d_in[11];
    const float* W4 = (const float*)d_in[12];
    const float* b4 = (const float*)d_in[13];
    float* out = (float*)d_out;

    float* W0p = (float*)d_ws;    // 32*128
    float* W4p = W0p + 32 * 128;  // 128*32
    float* b4p = W4p + 128 * 32;  // 32

    prep_kernel<<<16, 256, 0, stream>>>(W0, W4, b4, W0p, W4p, b4p);

    const int Npts = in_sizes[0] / 3;
    const int M = Npts * 6;
    const int blocks = (M + PB - 1) / PB;
    snarf_kernel<<<blocks, BLOCK, 0, stream>>>(
        x, bone_pts, transforms, delta_tf, W0p, b0, W1, b1, W2, b2, W3, b3,
        W4p, b4p, out, Npts);
}

// Round 6
// 8378.941 us; speedup vs baseline: 1.3926x; 1.3926x over previous
//
#include <hip/hip_runtime.h>
#include <math.h>

#define BLOCK 256
#define NPROB 64   // problems per block (16 per wave, 4 lanes per problem)
#define HSTR 65    // h row stride in floats (64 cols + 1 pad)

typedef float v2f __attribute__((ext_vector_type(2)));

__device__ __forceinline__ v2f mkv2(float a, float b) {
    v2f r; r.x = a; r.y = b; return r;
}
__device__ __forceinline__ v2f pkfma(v2f a, v2f b, v2f c) {
#if __has_builtin(__builtin_elementwise_fma)
    return __builtin_elementwise_fma(a, b, c);
#else
    return mkv2(fmaf(a.x, b.x, c.x), fmaf(a.y, b.y, c.y));
#endif
}

// prep: W0 [27][128] -> W0p [32][128] (zero rows); W4 [128][25] -> W4p [128][32]
// (zero cols); b4 [25] -> b4p [32]
__global__ void prep_kernel(const float* __restrict__ W0, const float* __restrict__ W4,
                            const float* __restrict__ b4, float* __restrict__ W0p,
                            float* __restrict__ W4p, float* __restrict__ b4p) {
    const int t = blockIdx.x * blockDim.x + threadIdx.x;
    if (t < 32 * 128) {
        const int k = t >> 7, j = t & 127;
        W0p[t] = (k < 27) ? W0[k * 128 + j] : 0.0f;
    }
    if (t < 128 * 32) {
        const int k = t >> 5, j = t & 31;
        W4p[t] = (j < 25) ? W4[k * 25 + j] : 0.0f;
    }
    if (t < 32) b4p[t] = (t < 25) ? b4[t] : 0.0f;
}

// 32 outputs over K rows; Wc = W + s*32 (row stride WSTRIDE); h at hc[k*HSTR]
template <int K, int WSTRIDE>
__device__ __forceinline__ void layer32(const float* __restrict__ Wc,
                                        const float* __restrict__ bc,
                                        const float* __restrict__ hc,
                                        v2f* __restrict__ acc) {
#pragma unroll
    for (int q = 0; q < 8; ++q) {
        const float4 bb = *(const float4*)(bc + q * 4);
        acc[q * 2 + 0] = mkv2(bb.x, bb.y);
        acc[q * 2 + 1] = mkv2(bb.z, bb.w);
    }
#pragma unroll 2
    for (int k = 0; k < K; ++k) {
        const float hk = hc[k * HSTR];
        const v2f hh = mkv2(hk, hk);
        const float* Wr = Wc + k * WSTRIDE;
#pragma unroll
        for (int q = 0; q < 8; ++q) {
            const float4 w = *(const float4*)(Wr + q * 4);
            acc[q * 2 + 0] = pkfma(hh, mkv2(w.x, w.y), acc[q * 2 + 0]);
            acc[q * 2 + 1] = pkfma(hh, mkv2(w.z, w.w), acc[q * 2 + 1]);
        }
    }
}

// 8 outputs over K rows; Wc = W4p + s*8 (row stride 32)
template <int K>
__device__ __forceinline__ void layer8(const float* __restrict__ Wc,
                                       const float* __restrict__ bc,
                                       const float* __restrict__ hc,
                                       v2f* __restrict__ acc) {
#pragma unroll
    for (int q = 0; q < 2; ++q) {
        const float4 bb = *(const float4*)(bc + q * 4);
        acc[q * 2 + 0] = mkv2(bb.x, bb.y);
        acc[q * 2 + 1] = mkv2(bb.z, bb.w);
    }
#pragma unroll 4
    for (int k = 0; k < K; ++k) {
        const float hk = hc[k * HSTR];
        const v2f hh = mkv2(hk, hk);
        const float* Wr = Wc + k * 32;
#pragma unroll
        for (int q = 0; q < 2; ++q) {
            const float4 w = *(const float4*)(Wr + q * 4);
            acc[q * 2 + 0] = pkfma(hh, mkv2(w.x, w.y), acc[q * 2 + 0]);
            acc[q * 2 + 1] = pkfma(hh, mkv2(w.z, w.w), acc[q * 2 + 1]);
        }
    }
}

__global__ __launch_bounds__(BLOCK) void snarf_kernel(
    const float* __restrict__ xin, const float* __restrict__ bone_pts,
    const float* __restrict__ transforms, const float* __restrict__ delta_tf,
    const float* __restrict__ W0p, const float* __restrict__ b0,
    const float* __restrict__ W1, const float* __restrict__ b1,
    const float* __restrict__ W2, const float* __restrict__ b2,
    const float* __restrict__ W3, const float* __restrict__ b3,
    const float* __restrict__ W4p, const float* __restrict__ b4p,
    float* __restrict__ out, int Npts) {
    __shared__ float hL[128 * HSTR];  // 33.3 KiB
    __shared__ int wflag[4];
    const int tid = threadIdx.x;
    const int wid = tid >> 6;
    const int lane = tid & 63;
    const int p16 = lane & 15;
    const int s = lane >> 4;                 // quarter 0..3
    const int pl = wid * 16 + p16;           // local problem 0..63
    const int M = Npts * 6;
    const int m = blockIdx.x * NPROB + pl;
    const int mc = (m < M) ? m : (M - 1);
    const int n = mc / 6;
    const int i = mc - n * 6;

    float* __restrict__ hc = &hL[pl];                  // my column
    float* __restrict__ hw = &hL[(s * 32) * HSTR + pl]; // my writeback rows

    const float tx = xin[n * 3 + 0], ty = xin[n * 3 + 1], tz = xin[n * 3 + 2];

    // ---- init candidate (duplicated across s; bitwise identical)
    float xk0, xk1, xk2;
    if (i < 5) {
        float dprev = -1.0f;
        int jprev = -1;
        for (int r = 0; r <= i; ++r) {
            float bd = 3.4028235e38f;
            int bj = 0;
            for (int j = 0; j < 24; ++j) {
                const float ax = tx - bone_pts[j * 3 + 0];
                const float ay = ty - bone_pts[j * 3 + 1];
                const float az = tz - bone_pts[j * 3 + 2];
                const float d = sqrtf(ax * ax + ay * ay + az * az);
                const bool taken = (d < dprev) || (d == dprev && j <= jprev);
                if (!taken && d < bd) { bd = d; bj = j; }
            }
            dprev = bd;
            jprev = bj;
        }
        const float* T = delta_tf + jprev * 16;
        xk0 = fmaf(T[0], tx, fmaf(T[1], ty, fmaf(T[2], tz, T[3])));
        xk1 = fmaf(T[4], tx, fmaf(T[5], ty, fmaf(T[6], tz, T[7])));
        xk2 = fmaf(T[8], tx, fmaf(T[9], ty, fmaf(T[10], tz, T[11])));
    } else {
        xk0 = tx; xk1 = ty; xk2 = tz;
    }

    // ---- Broyden state (duplicated across s)
    float gx0 = 0.f, gx1 = 0.f, gx2 = 0.f;
    float J00 = 1.f, J01 = 0.f, J02 = 0.f;
    float J10 = 0.f, J11 = 1.f, J12 = 0.f;
    float J20 = 0.f, J21 = 0.f, J22 = 1.f;
    float up0 = 0.f, up1 = 0.f, up2 = 0.f;
    float xo0 = xk0, xo1 = xk1, xo2 = xk2;
    float nopt = 0.f;
    float dx0 = 0.f, dx1 = 0.f, dx2 = 0.f;
    float dg0 = 0.f, dg1 = 0.f, dg2 = 0.f;
    bool mask = (m < M);

    v2f acc[16];

    int step = -1;  // -1 init eval, 0..7 Broyden, 8 final eval
    while (step <= 8) {
        bool m3 = mask;
        if (step >= 0 && step < 8) {
            const bool anyw = (__ballot(mask) != 0ull);
            if (lane == 0) wflag[wid] = anyw ? 1 : 0;
            __syncthreads();
            const int anyb = wflag[0] | wflag[1] | wflag[2] | wflag[3];
            __syncthreads();
            if (anyb == 0) { step = 8; continue; }
            if (m3) {
                dx0 = up0; dx1 = up1; dx2 = up2;
                xk0 += dx0; xk1 += dx1; xk2 += dx2;
            }
        } else if (step == 8) {
            __syncthreads();  // WAR: prior l25 reads vs pe writes below
        }
        float cx0 = xk0, cx1 = xk1, cx2 = xk2;
        if (step == 8) { cx0 = xo0; cx1 = xo1; cx2 = xo2; }

        // ---- positional encoding: all 12 sincos, each s-group stores its 8 rows
        float s1x, c1x, s1y, c1y, s1z, c1z;
        float s2x, c2x, s2y, c2y, s2z, c2z;
        float s4x, c4x, s4y, c4y, s4z, c4z;
        float s8x, c8x, s8y, c8y, s8z, c8z;
        sincosf(cx0, &s1x, &c1x); sincosf(cx1, &s1y, &c1y); sincosf(cx2, &s1z, &c1z);
        sincosf(2.f * cx0, &s2x, &c2x); sincosf(2.f * cx1, &s2y, &c2y); sincosf(2.f * cx2, &s2z, &c2z);
        sincosf(4.f * cx0, &s4x, &c4x); sincosf(4.f * cx1, &s4y, &c4y); sincosf(4.f * cx2, &s4z, &c4z);
        sincosf(8.f * cx0, &s8x, &c8x); sincosf(8.f * cx1, &s8y, &c8y); sincosf(8.f * cx2, &s8z, &c8z);
        if (s == 0) {
            hc[0 * HSTR] = cx0; hc[1 * HSTR] = cx1; hc[2 * HSTR] = cx2;
            hc[3 * HSTR] = s1x; hc[4 * HSTR] = s1y; hc[5 * HSTR] = s1z;
            hc[6 * HSTR] = s2x; hc[7 * HSTR] = s2y;
        } else if (s == 1) {
            hc[8 * HSTR] = s2z; hc[9 * HSTR] = s4x; hc[10 * HSTR] = s4y;
            hc[11 * HSTR] = s4z; hc[12 * HSTR] = s8x; hc[13 * HSTR] = s8y;
            hc[14 * HSTR] = s8z; hc[15 * HSTR] = c1x;
        } else if (s == 2) {
            hc[16 * HSTR] = c1y; hc[17 * HSTR] = c1z; hc[18 * HSTR] = c2x;
            hc[19 * HSTR] = c2y; hc[20 * HSTR] = c2z; hc[21 * HSTR] = c4x;
            hc[22 * HSTR] = c4y; hc[23 * HSTR] = c4z;
        } else {
            hc[24 * HSTR] = c8x; hc[25 * HSTR] = c8y; hc[26 * HSTR] = c8z;
            hc[27 * HSTR] = 0.f; hc[28 * HSTR] = 0.f; hc[29 * HSTR] = 0.f;
            hc[30 * HSTR] = 0.f; hc[31 * HSTR] = 0.f;
        }
        __syncthreads();

        layer32<32, 128>(W0p + s * 32, b0 + s * 32, hc, acc);
#pragma unroll
        for (int q = 0; q < 16; ++q) {
            hw[(2 * q) * HSTR] = fmaxf(acc[q].x, 0.f);
            hw[(2 * q + 1) * HSTR] = fmaxf(acc[q].y, 0.f);
        }
        __syncthreads();
        layer32<128, 128>(W1 + s * 32, b1 + s * 32, hc, acc);
#pragma unroll
        for (int q = 0; q < 16; ++q) {
            hw[(2 * q) * HSTR] = fmaxf(acc[q].x, 0.f);
            hw[(2 * q + 1) * HSTR] = fmaxf(acc[q].y, 0.f);
        }
        __syncthreads();
        layer32<128, 128>(W2 + s * 32, b2 + s * 32, hc, acc);
#pragma unroll
        for (int q = 0; q < 16; ++q) {
            hw[(2 * q) * HSTR] = fmaxf(acc[q].x, 0.f);
            hw[(2 * q + 1) * HSTR] = fmaxf(acc[q].y, 0.f);
        }
        __syncthreads();
        layer32<128, 128>(W3 + s * 32, b3 + s * 32, hc, acc);
#pragma unroll
        for (int q = 0; q < 16; ++q) {
            hw[(2 * q) * HSTR] = fmaxf(acc[q].x, 0.f);
            hw[(2 * q + 1) * HSTR] = fmaxf(acc[q].y, 0.f);
        }
        __syncthreads();

        // ---- output layer: my 8 of 32 padded logits
        layer8<128>(W4p + s * 8, b4p + s * 8, hc, acc);
        {
            const int base = s * 8;
            hc[(base + 0) * HSTR] = acc[0].x;
            hc[(base + 1) * HSTR] = acc[0].y;
            hc[(base + 2) * HSTR] = acc[1].x;
            hc[(base + 3) * HSTR] = acc[1].y;
            hc[(base + 4) * HSTR] = acc[2].x;
            hc[(base + 5) * HSTR] = acc[2].y;
            hc[(base + 6) * HSTR] = acc[3].x;
            hc[(base + 7) * HSTR] = acc[3].y;
        }
        __syncthreads();
        float l25[25];
#pragma unroll
        for (int j = 0; j < 25; ++j) l25[j] = hc[j * HSTR];

        // softmax(5 * logits) over 25 (duplicated across s, identical)
        float zm = -3.4028235e38f;
#pragma unroll
        for (int j = 0; j < 25; ++j) {
            l25[j] = 5.0f * l25[j];
            zm = fmaxf(zm, l25[j]);
        }
        float ssum = 0.f;
#pragma unroll
        for (int j = 0; j < 25; ++j) {
            l25[j] = expf(l25[j] - zm);
            ssum += l25[j];
        }
        const float inv = 1.0f / ssum;

        float tf[12];
#pragma unroll
        for (int r = 0; r < 12; ++r) tf[r] = 0.f;
#pragma unroll
        for (int j = 0; j < 24; ++j) {
            const float wj = l25[j] * inv;
            const float* T = transforms + j * 16;
#pragma unroll
            for (int r = 0; r < 12; ++r) tf[r] = fmaf(wj, T[r], tf[r]);
        }
        {
            const float wj = l25[24] * inv;  // identity transform
            tf[0] += wj; tf[5] += wj; tf[10] += wj;
        }
        const float r0 = fmaf(tf[0], cx0, fmaf(tf[1], cx1, fmaf(tf[2], cx2, tf[3])));
        const float r1 = fmaf(tf[4], cx0, fmaf(tf[5], cx1, fmaf(tf[6], cx2, tf[7])));
        const float r2 = fmaf(tf[8], cx0, fmaf(tf[9], cx1, fmaf(tf[10], cx2, tf[11])));

        if (step == 8) {
            if (s == 0 && m < M) {
                out[(size_t)m * 3 + 0] = r0;
                out[(size_t)m * 3 + 1] = r1;
                out[(size_t)m * 3 + 2] = r2;
                float* xopt_out = out + (size_t)M * 3;
                xopt_out[(size_t)m * 3 + 0] = xo0;
                xopt_out[(size_t)m * 3 + 1] = xo1;
                xopt_out[(size_t)m * 3 + 2] = xo2;
                out[(size_t)M * 6 + m] = nopt;
                out[(size_t)M * 7 + m] = (nopt < 1e-5f) ? 1.0f : 0.0f;
            }
            break;
        }

        const float g0 = r0 - tx, g1 = r1 - ty, g2 = r2 - tz;

        if (step == -1) {
            gx0 = g0; gx1 = g1; gx2 = g2;
            const float gn = sqrtf(g0 * g0 + g1 * g1 + g2 * g2);
            nopt = gn;
            up0 = -g0; up1 = -g1; up2 = -g2;  // Jinv = I
        } else {
            if (m3) {
                dg0 = g0 - gx0; dg1 = g1 - gx1; dg2 = g2 - gx2;
                gx0 += dg0; gx1 += dg1; gx2 += dg2;
            }
            const float gn = sqrtf(gx0 * gx0 + gx1 * gx1 + gx2 * gx2);
            const bool better = gn < nopt;
            if (better) {
                nopt = gn;
                xo0 = xk0; xo1 = xk1; xo2 = xk2;
            }
            mask = mask && (nopt > 1e-5f) && (gn < 1.0f);

            const float v0 = dx0 * J00 + dx1 * J10 + dx2 * J20;
            const float v1 = dx0 * J01 + dx1 * J11 + dx2 * J21;
            const float v2 = dx0 * J02 + dx1 * J12 + dx2 * J22;
            const float Jd0 = J00 * dg0 + J01 * dg1 + J02 * dg2;
            const float Jd1 = J10 * dg0 + J11 * dg1 + J12 * dg2;
            const float Jd2 = J20 * dg0 + J21 * dg1 + J22 * dg2;
            const float a0 = dx0 - Jd0, a1 = dx1 - Jd1, a2 = dx2 - Jd2;
            float bden = v0 * dg0 + v1 * dg1 + v2 * dg2;
            bden += (bden >= 0.f) ? 1e-6f : -1e-6f;
            if (mask) {
                const float q0 = a0 / bden, q1 = a1 / bden, q2 = a2 / bden;
                J00 = fmaf(q0, v0, J00); J01 = fmaf(q0, v1, J01); J02 = fmaf(q0, v2, J02);
                J10 = fmaf(q1, v0, J10); J11 = fmaf(q1, v1, J11); J12 = fmaf(q1, v2, J12);
                J20 = fmaf(q2, v0, J20); J21 = fmaf(q2, v1, J21); J22 = fmaf(q2, v2, J22);
            }
            if (m3) {
                up0 = -(J00 * gx0 + J01 * gx1 + J02 * gx2);
                up1 = -(J10 * gx0 + J11 * gx1 + J12 * gx2);
                up2 = -(J20 * gx0 + J21 * gx1 + J22 * gx2);
            }
        }
        ++step;
    }
}

extern "C" void kernel_launch(void* const* d_in, const int* in_sizes, int n_in,
                              void* d_out, int out_size, void* d_ws, size_t ws_size,
                              hipStream_t stream) {
    const float* x = (const float*)d_in[0];
    const float* bone_pts = (const float*)d_in[1];
    const float* transforms = (const float*)d_in[2];
    const float* delta_tf = (const float*)d_in[3];
    const float* W0 = (const float*)d_in[4];
    const float* b0 = (const float*)d_in[5];
    const float* W1 = (const float*)d_in[6];
    const float* b1 = (const float*)d_in[7];
    const float* W2 = (const float*)d_in[8];
    const float* b2 = (const float*)d_in[9];
    const float* W3 = (const float*)d_in[10];
    const float* b3 = (const float*)d_in[11];
    const float* W4 = (const float*)d_in[12];
    const float* b4 = (const float*)d_in[13];
    float* out = (float*)d_out;

    float* W0p = (float*)d_ws;    // 32*128
    float* W4p = W0p + 32 * 128;  // 128*32
    float* b4p = W4p + 128 * 32;  // 32

    prep_kernel<<<16, 256, 0, stream>>>(W0, W4, b4, W0p, W4p, b4p);

    const int Npts = in_sizes[0] / 3;
    const int M = Npts * 6;
    const int blocks = (M + NPROB - 1) / NPROB;
    snarf_kernel<<<blocks, BLOCK, 0, stream>>>(
        x, bone_pts, transforms, delta_tf, W0p, b0, W1, b1, W2, b2, W3, b3,
        W4p, b4p, out, Npts);
}

// Round 7
// 7678.471 us; speedup vs baseline: 1.5196x; 1.0912x over previous
//
#include <hip/hip_runtime.h>
#include <math.h>

#define BLOCK 256
#define NPROB 32   // problems per block: 8 per wave, 8 lanes per problem
#define HSTR 33    // h row stride in floats

typedef float v2f __attribute__((ext_vector_type(2)));

__device__ __forceinline__ v2f mkv2(float a, float b) {
    v2f r; r.x = a; r.y = b; return r;
}
__device__ __forceinline__ v2f pkfma(v2f a, v2f b, v2f c) {
#if __has_builtin(__builtin_elementwise_fma)
    return __builtin_elementwise_fma(a, b, c);
#else
    return mkv2(fmaf(a.x, b.x, c.x), fmaf(a.y, b.y, c.y));
#endif
}

// prep: W0 [27][128] -> W0p [32][128] (zero rows); W4 [128][25] -> W4p [128][32]
// (zero cols); b4 [25] -> b4p [32]
__global__ void prep_kernel(const float* __restrict__ W0, const float* __restrict__ W4,
                            const float* __restrict__ b4, float* __restrict__ W0p,
                            float* __restrict__ W4p, float* __restrict__ b4p) {
    const int t = blockIdx.x * blockDim.x + threadIdx.x;
    if (t < 32 * 128) {
        const int k = t >> 7, j = t & 127;
        W0p[t] = (k < 27) ? W0[k * 128 + j] : 0.0f;
    }
    if (t < 128 * 32) {
        const int k = t >> 5, j = t & 31;
        W4p[t] = (j < 25) ? W4[k * 25 + j] : 0.0f;
    }
    if (t < 32) b4p[t] = (t < 25) ? b4[t] : 0.0f;
}

// 16 outputs over K rows. Wc = W + s*16 (row stride WS); h at hds[k*HSTR].
// unroll 4 -> 16 independent float4 loads per body for deep ILP.
template <int K, int WS>
__device__ __forceinline__ void layer16(const float* __restrict__ Wc,
                                        const float* __restrict__ bc,
                                        const float* __restrict__ hds,
                                        v2f* __restrict__ acc) {
#pragma unroll
    for (int q = 0; q < 4; ++q) {
        const float4 bb = *(const float4*)(bc + q * 4);
        acc[2 * q + 0] = mkv2(bb.x, bb.y);
        acc[2 * q + 1] = mkv2(bb.z, bb.w);
    }
#pragma unroll 4
    for (int k = 0; k < K; ++k) {
        const float hk = hds[k * HSTR];
        const float* Wr = Wc + k * WS;
        const float4 w0 = *(const float4*)(Wr + 0);
        const float4 w1 = *(const float4*)(Wr + 4);
        const float4 w2 = *(const float4*)(Wr + 8);
        const float4 w3 = *(const float4*)(Wr + 12);
        const v2f hh = mkv2(hk, hk);
        acc[0] = pkfma(hh, mkv2(w0.x, w0.y), acc[0]);
        acc[1] = pkfma(hh, mkv2(w0.z, w0.w), acc[1]);
        acc[2] = pkfma(hh, mkv2(w1.x, w1.y), acc[2]);
        acc[3] = pkfma(hh, mkv2(w1.z, w1.w), acc[3]);
        acc[4] = pkfma(hh, mkv2(w2.x, w2.y), acc[4]);
        acc[5] = pkfma(hh, mkv2(w2.z, w2.w), acc[5]);
        acc[6] = pkfma(hh, mkv2(w3.x, w3.y), acc[6]);
        acc[7] = pkfma(hh, mkv2(w3.z, w3.w), acc[7]);
    }
}

// 4 outputs over 128 rows; Wc = W4p + s*4 (row stride 32)
__device__ __forceinline__ void layer4(const float* __restrict__ Wc,
                                       const float* __restrict__ bc,
                                       const float* __restrict__ hds,
                                       v2f* __restrict__ acc) {
    const float4 bb = *(const float4*)bc;
    acc[0] = mkv2(bb.x, bb.y);
    acc[1] = mkv2(bb.z, bb.w);
#pragma unroll 8
    for (int k = 0; k < 128; ++k) {
        const float hk = hds[k * HSTR];
        const float4 w = *(const float4*)(Wc + k * 32);
        const v2f hh = mkv2(hk, hk);
        acc[0] = pkfma(hh, mkv2(w.x, w.y), acc[0]);
        acc[1] = pkfma(hh, mkv2(w.z, w.w), acc[1]);
    }
}

// LDS-parked per-thread solver state slots:
// 0..8 J, 9..11 up, 12..14 dx, 15..17 dg, 18..20 xo, 21 nopt
__global__ __launch_bounds__(BLOCK, 4) void snarf_kernel(
    const float* __restrict__ xin, const float* __restrict__ bone_pts,
    const float* __restrict__ transforms, const float* __restrict__ delta_tf,
    const float* __restrict__ W0p, const float* __restrict__ b0,
    const float* __restrict__ W1, const float* __restrict__ b1,
    const float* __restrict__ W2, const float* __restrict__ b2,
    const float* __restrict__ W3, const float* __restrict__ b3,
    const float* __restrict__ W4p, const float* __restrict__ b4p,
    float* __restrict__ out, int Npts) {
    __shared__ float hL[128 * HSTR];   // 16896 B
    __shared__ float stL[22 * BLOCK];  // 22528 B  (total 39424 B -> 4 blocks/CU)
    const int tid = threadIdx.x;
    const int wid = tid >> 6;
    const int lane = tid & 63;
    const int s = lane >> 3;             // 0..7: my 16-col slice
    const int p8 = lane & 7;
    const int pl = wid * 8 + p8;         // local problem 0..31
    const int M = Npts * 6;
    const int m = blockIdx.x * NPROB + pl;
    const int mc = (m < M) ? m : (M - 1);
    const int n = mc / 6;
    const int i = mc - n * 6;

    float* __restrict__ hds = &hL[pl];
    volatile float* st = &stL[tid];
#define STS(idx) st[(idx) * BLOCK]

    const float tx = xin[n * 3 + 0], ty = xin[n * 3 + 1], tz = xin[n * 3 + 2];

    // ---- init candidate (duplicated across s; bitwise identical)
    float xk0, xk1, xk2;
    if (i < 5) {
        float dprev = -1.0f;
        int jprev = -1;
        for (int r = 0; r <= i; ++r) {
            float bd = 3.4028235e38f;
            int bj = 0;
            for (int j = 0; j < 24; ++j) {
                const float ax = tx - bone_pts[j * 3 + 0];
                const float ay = ty - bone_pts[j * 3 + 1];
                const float az = tz - bone_pts[j * 3 + 2];
                const float d = sqrtf(ax * ax + ay * ay + az * az);
                const bool taken = (d < dprev) || (d == dprev && j <= jprev);
                if (!taken && d < bd) { bd = d; bj = j; }
            }
            dprev = bd;
            jprev = bj;
        }
        const float* T = delta_tf + jprev * 16;
        xk0 = fmaf(T[0], tx, fmaf(T[1], ty, fmaf(T[2], tz, T[3])));
        xk1 = fmaf(T[4], tx, fmaf(T[5], ty, fmaf(T[6], tz, T[7])));
        xk2 = fmaf(T[8], tx, fmaf(T[9], ty, fmaf(T[10], tz, T[11])));
    } else {
        xk0 = tx; xk1 = ty; xk2 = tz;
    }

    float gx0 = 0.f, gx1 = 0.f, gx2 = 0.f;
    bool mask = (m < M);

    v2f acc[8];

    int step = -1;  // -1 init eval, 0..7 Broyden, 8 final eval
    while (step <= 8) {
        bool m3 = mask;
        if (step >= 0 && step < 8) {
            if (__ballot(mask) == 0ull) { step = 8; continue; }
            if (m3) {
                const float u0 = STS(9), u1 = STS(10), u2 = STS(11);
                STS(12) = u0; STS(13) = u1; STS(14) = u2;  // dx = up
                xk0 += u0; xk1 += u1; xk2 += u2;
            }
        }
        float cx0 = xk0, cx1 = xk1, cx2 = xk2;
        if (step == 8) { cx0 = STS(18); cx1 = STS(19); cx2 = STS(20); }

        // ---- positional encoding: every lane computes + writes all 32 rows
        float pe[32];
        pe[0] = cx0; pe[1] = cx1; pe[2] = cx2;
#pragma unroll
        for (int sc = 0; sc < 4; ++sc) {
            const float f = (float)(1 << sc);
            float sx, cxx, sy, cyy, sz, czz;
            sincosf(f * cx0, &sx, &cxx);
            sincosf(f * cx1, &sy, &cyy);
            sincosf(f * cx2, &sz, &czz);
            pe[3 + sc * 3 + 0] = sx;
            pe[3 + sc * 3 + 1] = sy;
            pe[3 + sc * 3 + 2] = sz;
            pe[15 + sc * 3 + 0] = cxx;
            pe[15 + sc * 3 + 1] = cyy;
            pe[15 + sc * 3 + 2] = czz;
        }
#pragma unroll
        for (int j = 27; j < 32; ++j) pe[j] = 0.0f;
#pragma unroll
        for (int j = 0; j < 32; ++j) hds[j * HSTR] = pe[j];

        layer16<32, 128>(W0p + s * 16, b0 + s * 16, hds, acc);
        {
            float* hw = &hL[(s * 16) * HSTR + pl];
#pragma unroll
            for (int q = 0; q < 8; ++q) {
                hw[(2 * q) * HSTR] = fmaxf(acc[q].x, 0.f);
                hw[(2 * q + 1) * HSTR] = fmaxf(acc[q].y, 0.f);
            }
        }
        layer16<128, 128>(W1 + s * 16, b1 + s * 16, hds, acc);
        {
            float* hw = &hL[(s * 16) * HSTR + pl];
#pragma unroll
            for (int q = 0; q < 8; ++q) {
                hw[(2 * q) * HSTR] = fmaxf(acc[q].x, 0.f);
                hw[(2 * q + 1) * HSTR] = fmaxf(acc[q].y, 0.f);
            }
        }
        layer16<128, 128>(W2 + s * 16, b2 + s * 16, hds, acc);
        {
            float* hw = &hL[(s * 16) * HSTR + pl];
#pragma unroll
            for (int q = 0; q < 8; ++q) {
                hw[(2 * q) * HSTR] = fmaxf(acc[q].x, 0.f);
                hw[(2 * q + 1) * HSTR] = fmaxf(acc[q].y, 0.f);
            }
        }
        layer16<128, 128>(W3 + s * 16, b3 + s * 16, hds, acc);
        {
            float* hw = &hL[(s * 16) * HSTR + pl];
#pragma unroll
            for (int q = 0; q < 8; ++q) {
                hw[(2 * q) * HSTR] = fmaxf(acc[q].x, 0.f);
                hw[(2 * q + 1) * HSTR] = fmaxf(acc[q].y, 0.f);
            }
        }
        // ---- output layer: my 4 of 32 padded logits, exchange through LDS rows 0..31
        layer4(W4p + s * 4, b4p + s * 4, hds, acc);
        hds[(s * 4 + 0) * HSTR] = acc[0].x;
        hds[(s * 4 + 1) * HSTR] = acc[0].y;
        hds[(s * 4 + 2) * HSTR] = acc[1].x;
        hds[(s * 4 + 3) * HSTR] = acc[1].y;
        float l25[25];
#pragma unroll
        for (int j = 0; j < 25; ++j) l25[j] = hds[j * HSTR];

        // softmax(5 * logits) over 25 (duplicated across s, identical)
        float zm = -3.4028235e38f;
#pragma unroll
        for (int j = 0; j < 25; ++j) {
            l25[j] = 5.0f * l25[j];
            zm = fmaxf(zm, l25[j]);
        }
        float ssum = 0.f;
#pragma unroll
        for (int j = 0; j < 25; ++j) {
            l25[j] = expf(l25[j] - zm);
            ssum += l25[j];
        }
        const float inv = 1.0f / ssum;

        float tf[12];
#pragma unroll
        for (int r = 0; r < 12; ++r) tf[r] = 0.f;
#pragma unroll
        for (int j = 0; j < 24; ++j) {
            const float wj = l25[j] * inv;
            const float* T = transforms + j * 16;
#pragma unroll
            for (int r = 0; r < 12; ++r) tf[r] = fmaf(wj, T[r], tf[r]);
        }
        {
            const float wj = l25[24] * inv;  // identity transform
            tf[0] += wj; tf[5] += wj; tf[10] += wj;
        }
        const float r0 = fmaf(tf[0], cx0, fmaf(tf[1], cx1, fmaf(tf[2], cx2, tf[3])));
        const float r1 = fmaf(tf[4], cx0, fmaf(tf[5], cx1, fmaf(tf[6], cx2, tf[7])));
        const float r2 = fmaf(tf[8], cx0, fmaf(tf[9], cx1, fmaf(tf[10], cx2, tf[11])));

        if (step == 8) {
            if (s == 0 && m < M) {
                const float nopt = STS(21);
                out[(size_t)m * 3 + 0] = r0;
                out[(size_t)m * 3 + 1] = r1;
                out[(size_t)m * 3 + 2] = r2;
                float* xopt_out = out + (size_t)M * 3;
                xopt_out[(size_t)m * 3 + 0] = cx0;
                xopt_out[(size_t)m * 3 + 1] = cx1;
                xopt_out[(size_t)m * 3 + 2] = cx2;
                out[(size_t)M * 6 + m] = nopt;
                out[(size_t)M * 7 + m] = (nopt < 1e-5f) ? 1.0f : 0.0f;
            }
            break;
        }

        const float g0 = r0 - tx, g1 = r1 - ty, g2 = r2 - tz;

        if (step == -1) {
            gx0 = g0; gx1 = g1; gx2 = g2;
            const float gn = sqrtf(g0 * g0 + g1 * g1 + g2 * g2);
            STS(21) = gn;                                  // nopt
            STS(9) = -g0; STS(10) = -g1; STS(11) = -g2;    // up (Jinv = I)
            STS(18) = xk0; STS(19) = xk1; STS(20) = xk2;   // xo
            STS(12) = 0.f; STS(13) = 0.f; STS(14) = 0.f;   // dx
            STS(15) = 0.f; STS(16) = 0.f; STS(17) = 0.f;   // dg
            STS(0) = 1.f; STS(1) = 0.f; STS(2) = 0.f;
            STS(3) = 0.f; STS(4) = 1.f; STS(5) = 0.f;
            STS(6) = 0.f; STS(7) = 0.f; STS(8) = 1.f;
        } else {
            float J00 = STS(0), J01 = STS(1), J02 = STS(2);
            float J10 = STS(3), J11 = STS(4), J12 = STS(5);
            float J20 = STS(6), J21 = STS(7), J22 = STS(8);
            const float dx0 = STS(12), dx1 = STS(13), dx2 = STS(14);
            float dg0 = STS(15), dg1 = STS(16), dg2 = STS(17);
            float nopt = STS(21);
            if (m3) {
                dg0 = g0 - gx0; dg1 = g1 - gx1; dg2 = g2 - gx2;
                gx0 += dg0; gx1 += dg1; gx2 += dg2;
                STS(15) = dg0; STS(16) = dg1; STS(17) = dg2;
            }
            const float gn = sqrtf(gx0 * gx0 + gx1 * gx1 + gx2 * gx2);
            const bool better = gn < nopt;
            if (better) {
                nopt = gn;
                STS(21) = gn;
                STS(18) = xk0; STS(19) = xk1; STS(20) = xk2;
            }
            mask = (nopt > 1e-5f) && (gn < 1.0f) && (m < M);

            const float v0 = dx0 * J00 + dx1 * J10 + dx2 * J20;
            const float v1 = dx0 * J01 + dx1 * J11 + dx2 * J21;
            const float v2 = dx0 * J02 + dx1 * J12 + dx2 * J22;
            const float Jd0 = J00 * dg0 + J01 * dg1 + J02 * dg2;
            const float Jd1 = J10 * dg0 + J11 * dg1 + J12 * dg2;
            const float Jd2 = J20 * dg0 + J21 * dg1 + J22 * dg2;
            const float a0 = dx0 - Jd0, a1 = dx1 - Jd1, a2 = dx2 - Jd2;
            float bden = v0 * dg0 + v1 * dg1 + v2 * dg2;
            bden += (bden >= 0.f) ? 1e-6f : -1e-6f;
            if (mask) {
                const float q0 = a0 / bden, q1 = a1 / bden, q2 = a2 / bden;
                J00 = fmaf(q0, v0, J00); J01 = fmaf(q0, v1, J01); J02 = fmaf(q0, v2, J02);
                J10 = fmaf(q1, v0, J10); J11 = fmaf(q1, v1, J11); J12 = fmaf(q1, v2, J12);
                J20 = fmaf(q2, v0, J20); J21 = fmaf(q2, v1, J21); J22 = fmaf(q2, v2, J22);
                STS(0) = J00; STS(1) = J01; STS(2) = J02;
                STS(3) = J10; STS(4) = J11; STS(5) = J12;
                STS(6) = J20; STS(7) = J21; STS(8) = J22;
            }
            if (m3) {
                STS(9) = -(J00 * gx0 + J01 * gx1 + J02 * gx2);
                STS(10) = -(J10 * gx0 + J11 * gx1 + J12 * gx2);
                STS(11) = -(J20 * gx0 + J21 * gx1 + J22 * gx2);
            }
        }
        ++step;
    }
#undef STS
}

extern "C" void kernel_launch(void* const* d_in, const int* in_sizes, int n_in,
                              void* d_out, int out_size, void* d_ws, size_t ws_size,
                              hipStream_t stream) {
    const float* x = (const float*)d_in[0];
    const float* bone_pts = (const float*)d_in[1];
    const float* transforms = (const float*)d_in[2];
    const float* delta_tf = (const float*)d_in[3];
    const float* W0 = (const float*)d_in[4];
    const float* b0 = (const float*)d_in[5];
    const float* W1 = (const float*)d_in[6];
    const float* b1 = (const float*)d_in[7];
    const float* W2 = (const float*)d_in[8];
    const float* b2 = (const float*)d_in[9];
    const float* W3 = (const float*)d_in[10];
    const float* b3 = (const float*)d_in[11];
    const float* W4 = (const float*)d_in[12];
    const float* b4 = (const float*)d_in[13];
    float* out = (float*)d_out;

    float* W0p = (float*)d_ws;    // 32*128
    float* W4p = W0p + 32 * 128;  // 128*32
    float* b4p = W4p + 128 * 32;  // 32

    prep_kernel<<<16, 256, 0, stream>>>(W0, W4, b4, W0p, W4p, b4p);

    const int Npts = in_sizes[0] / 3;
    const int M = Npts * 6;
    const int blocks = (M + NPROB - 1) / NPROB;
    snarf_kernel<<<blocks, BLOCK, 0, stream>>>(
        x, bone_pts, transforms, delta_tf, W0p, b0, W1, b1, W2, b2, W3, b3,
        W4p, b4p, out, Npts);
}

// Round 8
// 2584.896 us; speedup vs baseline: 4.5141x; 2.9705x over previous
//
#include <hip/hip_runtime.h>
#include <math.h>

#define BLOCK 256
#define PPB 64     // problems per block (16 per wave)
#define HP 132     // floats per problem h-column (128 + 4 pad)

typedef float v2f __attribute__((ext_vector_type(2)));

__device__ __forceinline__ v2f mkv2(float a, float b) {
    v2f r; r.x = a; r.y = b; return r;
}
__device__ __forceinline__ v2f pkfma(v2f a, v2f b, v2f c) {
#if __has_builtin(__builtin_elementwise_fma)
    return __builtin_elementwise_fma(a, b, c);
#else
    return mkv2(fmaf(a.x, b.x, c.x), fmaf(a.y, b.y, c.y));
#endif
}

// prep: W0 [27][128] -> W0p [32][128] (zero rows); W4 [128][25] -> W4p [128][32]
// (zero cols); b4 [25] -> b4p [32]
__global__ void prep_kernel(const float* __restrict__ W0, const float* __restrict__ W4,
                            const float* __restrict__ b4, float* __restrict__ W0p,
                            float* __restrict__ W4p, float* __restrict__ b4p) {
    const int t = blockIdx.x * blockDim.x + threadIdx.x;
    if (t < 32 * 128) {
        const int k = t >> 7, j = t & 127;
        W0p[t] = (k < 27) ? W0[k * 128 + j] : 0.0f;
    }
    if (t < 128 * 32) {
        const int k = t >> 5, j = t & 31;
        W4p[t] = (j < 25) ? W4[k * 25 + j] : 0.0f;
    }
    if (t < 32) b4p[t] = (t < 25) ? b4[t] : 0.0f;
}

// main layer: lane owns 8 cols x 4 probs. Wc = W + 8*cg (row stride WS),
// bc = b + 8*cg, hg = h base of prob group (4*gg), hwr = hg + 8*cg.
// Reads h rows 0..K-1, writes ReLU'd outputs to h rows 8cg..8cg+8 (own probs).
// NOTE: h pointers intentionally NOT __restrict__ (same buffer, lockstep wave
// ordering makes read-then-write safe; restrict would license illegal reorder).
template <int K, int WS>
__device__ __forceinline__ void layerM(const float* __restrict__ Wc,
                                       const float* __restrict__ bc,
                                       const float* hg, float* hwr) {
    v2f acc[16];
    const float4 b0 = *(const float4*)(bc);
    const float4 b1 = *(const float4*)(bc + 4);
#pragma unroll
    for (int p = 0; p < 4; ++p) {
        acc[p * 4 + 0] = mkv2(b0.x, b0.y);
        acc[p * 4 + 1] = mkv2(b0.z, b0.w);
        acc[p * 4 + 2] = mkv2(b1.x, b1.y);
        acc[p * 4 + 3] = mkv2(b1.z, b1.w);
    }
#pragma unroll 4
    for (int k = 0; k < K; ++k) {
        const float4 w0 = *(const float4*)(Wc + k * WS);
        const float4 w1 = *(const float4*)(Wc + k * WS + 4);
        const float h0 = hg[0 * HP + k];
        const float h1 = hg[1 * HP + k];
        const float h2 = hg[2 * HP + k];
        const float h3 = hg[3 * HP + k];
        const v2f wa = mkv2(w0.x, w0.y), wb = mkv2(w0.z, w0.w);
        const v2f wc = mkv2(w1.x, w1.y), wd = mkv2(w1.z, w1.w);
        v2f hh;
        hh = mkv2(h0, h0);
        acc[0] = pkfma(hh, wa, acc[0]);  acc[1] = pkfma(hh, wb, acc[1]);
        acc[2] = pkfma(hh, wc, acc[2]);  acc[3] = pkfma(hh, wd, acc[3]);
        hh = mkv2(h1, h1);
        acc[4] = pkfma(hh, wa, acc[4]);  acc[5] = pkfma(hh, wb, acc[5]);
        acc[6] = pkfma(hh, wc, acc[6]);  acc[7] = pkfma(hh, wd, acc[7]);
        hh = mkv2(h2, h2);
        acc[8] = pkfma(hh, wa, acc[8]);  acc[9] = pkfma(hh, wb, acc[9]);
        acc[10] = pkfma(hh, wc, acc[10]); acc[11] = pkfma(hh, wd, acc[11]);
        hh = mkv2(h3, h3);
        acc[12] = pkfma(hh, wa, acc[12]); acc[13] = pkfma(hh, wb, acc[13]);
        acc[14] = pkfma(hh, wc, acc[14]); acc[15] = pkfma(hh, wd, acc[15]);
    }
#pragma unroll
    for (int p = 0; p < 4; ++p) {
        float4 o0, o1;
        o0.x = fmaxf(acc[p * 4 + 0].x, 0.f); o0.y = fmaxf(acc[p * 4 + 0].y, 0.f);
        o0.z = fmaxf(acc[p * 4 + 1].x, 0.f); o0.w = fmaxf(acc[p * 4 + 1].y, 0.f);
        o1.x = fmaxf(acc[p * 4 + 2].x, 0.f); o1.y = fmaxf(acc[p * 4 + 2].y, 0.f);
        o1.z = fmaxf(acc[p * 4 + 3].x, 0.f); o1.w = fmaxf(acc[p * 4 + 3].y, 0.f);
        *(float4*)(hwr + p * HP) = o0;
        *(float4*)(hwr + p * HP + 4) = o1;
    }
}

__global__ __launch_bounds__(BLOCK)
__attribute__((amdgpu_num_vgpr(128))) void snarf_kernel(
    const float* __restrict__ xin, const float* __restrict__ bone_pts,
    const float* __restrict__ transforms, const float* __restrict__ delta_tf,
    const float* __restrict__ W0p, const float* __restrict__ b0,
    const float* __restrict__ W1, const float* __restrict__ b1,
    const float* __restrict__ W2, const float* __restrict__ b2,
    const float* __restrict__ W3, const float* __restrict__ b3,
    const float* __restrict__ W4p, const float* __restrict__ b4p,
    float* __restrict__ out, int Npts) {
    __shared__ float hL[PPB * HP];      // 33792 B, h[prob][k]
    __shared__ float stL[22 * PPB];     // 5632 B solver state  (total 39424 B)
    const int tid = threadIdx.x;
    const int wid = tid >> 6;
    const int lane = tid & 63;
    const int p16 = lane & 15;   // my prob (epilogue/pe/last-layer mapping)
    const int sq = lane >> 4;    // duplicate group 0..3
    const int cg = lane >> 2;    // main-layer col group 0..15 (8 cols)
    const int gg = lane & 3;     // main-layer prob group 0..3 (4 probs)
    const int M = Npts * 6;
    const int m = blockIdx.x * PPB + wid * 16 + p16;
    const int mc = (m < M) ? m : (M - 1);
    const int n = mc / 6;
    const int i = mc - n * 6;

    float* hWv = &hL[wid * 16 * HP];          // wave's 16 prob columns
    const float* hg = hWv + (4 * gg) * HP;    // k-loop read base (4 probs)
    float* hwr = hWv + (4 * gg) * HP + 8 * cg;
    float* hq = hWv + p16 * HP;               // my prob's column
    volatile float* st = &stL[wid * 16 + p16];
#define STS(idx) st[(idx) * PPB]

    const float tx = xin[n * 3 + 0], ty = xin[n * 3 + 1], tz = xin[n * 3 + 2];

    // ---- init candidate (duplicated across sq; bitwise identical)
    float xk0, xk1, xk2;
    if (i < 5) {
        float dprev = -1.0f;
        int jprev = -1;
        for (int r = 0; r <= i; ++r) {
            float bd = 3.4028235e38f;
            int bj = 0;
            for (int j = 0; j < 24; ++j) {
                const float ax = tx - bone_pts[j * 3 + 0];
                const float ay = ty - bone_pts[j * 3 + 1];
                const float az = tz - bone_pts[j * 3 + 2];
                const float d = sqrtf(ax * ax + ay * ay + az * az);
                const bool taken = (d < dprev) || (d == dprev && j <= jprev);
                if (!taken && d < bd) { bd = d; bj = j; }
            }
            dprev = bd;
            jprev = bj;
        }
        const float* T = delta_tf + jprev * 16;
        xk0 = fmaf(T[0], tx, fmaf(T[1], ty, fmaf(T[2], tz, T[3])));
        xk1 = fmaf(T[4], tx, fmaf(T[5], ty, fmaf(T[6], tz, T[7])));
        xk2 = fmaf(T[8], tx, fmaf(T[9], ty, fmaf(T[10], tz, T[11])));
    } else {
        xk0 = tx; xk1 = ty; xk2 = tz;
    }

    float gx0 = 0.f, gx1 = 0.f, gx2 = 0.f;
    bool mask = (m < M);

    int step = -1;  // -1 init eval, 0..7 Broyden, 8 final eval
    while (step <= 8) {
        bool m3 = mask;
        if (step >= 0 && step < 8) {
            if (__ballot(mask) == 0ull) { step = 8; continue; }  // wave-local exit
            if (m3) {
                const float u0 = STS(9), u1 = STS(10), u2 = STS(11);
                STS(12) = u0; STS(13) = u1; STS(14) = u2;  // dx = up
                xk0 += u0; xk1 += u1; xk2 += u2;
            }
        }
        float cx0 = xk0, cx1 = xk1, cx2 = xk2;
        if (step == 8) { cx0 = STS(18); cx1 = STS(19); cx2 = STS(20); }

        // ---- positional encoding: all 12 sincos (dup x4); sq writes its 8 rows
        float s1x, c1x, s1y, c1y, s1z, c1z;
        float s2x, c2x, s2y, c2y, s2z, c2z;
        float s4x, c4x, s4y, c4y, s4z, c4z;
        float s8x, c8x, s8y, c8y, s8z, c8z;
        sincosf(cx0, &s1x, &c1x); sincosf(cx1, &s1y, &c1y); sincosf(cx2, &s1z, &c1z);
        sincosf(2.f * cx0, &s2x, &c2x); sincosf(2.f * cx1, &s2y, &c2y); sincosf(2.f * cx2, &s2z, &c2z);
        sincosf(4.f * cx0, &s4x, &c4x); sincosf(4.f * cx1, &s4y, &c4y); sincosf(4.f * cx2, &s4z, &c4z);
        sincosf(8.f * cx0, &s8x, &c8x); sincosf(8.f * cx1, &s8y, &c8y); sincosf(8.f * cx2, &s8z, &c8z);
        {
            float4 a, b;
            if (sq == 0) {
                a.x = cx0; a.y = cx1; a.z = cx2; a.w = s1x;
                b.x = s1y; b.y = s1z; b.z = s2x; b.w = s2y;
            } else if (sq == 1) {
                a.x = s2z; a.y = s4x; a.z = s4y; a.w = s4z;
                b.x = s8x; b.y = s8y; b.z = s8z; b.w = c1x;
            } else if (sq == 2) {
                a.x = c1y; a.y = c1z; a.z = c2x; a.w = c2y;
                b.x = c2z; b.y = c4x; b.z = c4y; b.w = c4z;
            } else {
                a.x = c8x; a.y = c8y; a.z = c8z; a.w = 0.f;
                b.x = 0.f; b.y = 0.f; b.z = 0.f; b.w = 0.f;
            }
            *(float4*)(hq + sq * 8) = a;
            *(float4*)(hq + sq * 8 + 4) = b;
        }

        layerM<32, 128>(W0p + 8 * cg, b0 + 8 * cg, hg, hwr);
        layerM<128, 128>(W1 + 8 * cg, b1 + 8 * cg, hg, hwr);
        layerM<128, 128>(W2 + 8 * cg, b2 + 8 * cg, hg, hwr);
        layerM<128, 128>(W3 + 8 * cg, b3 + 8 * cg, hg, hwr);

        // ---- output layer: lane (sq, p16) computes cols 8sq..8sq+8 of prob p16
        {
            v2f la[4];
            const float* bc = b4p + 8 * sq;
            const float4 bb0 = *(const float4*)(bc);
            const float4 bb1 = *(const float4*)(bc + 4);
            la[0] = mkv2(bb0.x, bb0.y); la[1] = mkv2(bb0.z, bb0.w);
            la[2] = mkv2(bb1.x, bb1.y); la[3] = mkv2(bb1.z, bb1.w);
            const float* Wc = W4p + 8 * sq;
#pragma unroll 4
            for (int k = 0; k < 128; ++k) {
                const float4 w0 = *(const float4*)(Wc + k * 32);
                const float4 w1 = *(const float4*)(Wc + k * 32 + 4);
                const float hk = hq[k];
                const v2f hh = mkv2(hk, hk);
                la[0] = pkfma(hh, mkv2(w0.x, w0.y), la[0]);
                la[1] = pkfma(hh, mkv2(w0.z, w0.w), la[1]);
                la[2] = pkfma(hh, mkv2(w1.x, w1.y), la[2]);
                la[3] = pkfma(hh, mkv2(w1.z, w1.w), la[3]);
            }
            float4 o0, o1;
            o0.x = la[0].x; o0.y = la[0].y; o0.z = la[1].x; o0.w = la[1].y;
            o1.x = la[2].x; o1.y = la[2].y; o1.z = la[3].x; o1.w = la[3].y;
            *(float4*)(hq + 8 * sq) = o0;
            *(float4*)(hq + 8 * sq + 4) = o1;
        }

        // ---- read 25 logits for my prob (dup x4)
        float l25[25];
        {
            const float4 r0 = *(const float4*)(hq + 0);
            const float4 r1 = *(const float4*)(hq + 4);
            const float4 r2 = *(const float4*)(hq + 8);
            const float4 r3 = *(const float4*)(hq + 12);
            const float4 r4 = *(const float4*)(hq + 16);
            const float4 r5 = *(const float4*)(hq + 20);
            l25[0] = r0.x; l25[1] = r0.y; l25[2] = r0.z; l25[3] = r0.w;
            l25[4] = r1.x; l25[5] = r1.y; l25[6] = r1.z; l25[7] = r1.w;
            l25[8] = r2.x; l25[9] = r2.y; l25[10] = r2.z; l25[11] = r2.w;
            l25[12] = r3.x; l25[13] = r3.y; l25[14] = r3.z; l25[15] = r3.w;
            l25[16] = r4.x; l25[17] = r4.y; l25[18] = r4.z; l25[19] = r4.w;
            l25[20] = r5.x; l25[21] = r5.y; l25[22] = r5.z; l25[23] = r5.w;
            l25[24] = hq[24];
        }

        // softmax(5 * logits) over 25
        float zm = -3.4028235e38f;
#pragma unroll
        for (int j = 0; j < 25; ++j) {
            l25[j] = 5.0f * l25[j];
            zm = fmaxf(zm, l25[j]);
        }
        float ssum = 0.f;
#pragma unroll
        for (int j = 0; j < 25; ++j) {
            l25[j] = expf(l25[j] - zm);
            ssum += l25[j];
        }
        const float inv = 1.0f / ssum;

        float tf[12];
#pragma unroll
        for (int r = 0; r < 12; ++r) tf[r] = 0.f;
#pragma unroll
        for (int j = 0; j < 24; ++j) {
            const float wj = l25[j] * inv;
            const float* T = transforms + j * 16;
#pragma unroll
            for (int r = 0; r < 12; ++r) tf[r] = fmaf(wj, T[r], tf[r]);
        }
        {
            const float wj = l25[24] * inv;  // identity transform
            tf[0] += wj; tf[5] += wj; tf[10] += wj;
        }
        const float r0 = fmaf(tf[0], cx0, fmaf(tf[1], cx1, fmaf(tf[2], cx2, tf[3])));
        const float r1 = fmaf(tf[4], cx0, fmaf(tf[5], cx1, fmaf(tf[6], cx2, tf[7])));
        const float r2 = fmaf(tf[8], cx0, fmaf(tf[9], cx1, fmaf(tf[10], cx2, tf[11])));

        if (step == 8) {
            if (sq == 0 && m < M) {
                const float nopt = STS(21);
                out[(size_t)m * 3 + 0] = r0;
                out[(size_t)m * 3 + 1] = r1;
                out[(size_t)m * 3 + 2] = r2;
                float* xopt_out = out + (size_t)M * 3;
                xopt_out[(size_t)m * 3 + 0] = cx0;
                xopt_out[(size_t)m * 3 + 1] = cx1;
                xopt_out[(size_t)m * 3 + 2] = cx2;
                out[(size_t)M * 6 + m] = nopt;
                out[(size_t)M * 7 + m] = (nopt < 1e-5f) ? 1.0f : 0.0f;
            }
            break;
        }

        const float g0 = r0 - tx, g1 = r1 - ty, g2 = r2 - tz;

        if (step == -1) {
            gx0 = g0; gx1 = g1; gx2 = g2;
            const float gn = sqrtf(g0 * g0 + g1 * g1 + g2 * g2);
            STS(21) = gn;                                  // nopt
            STS(9) = -g0; STS(10) = -g1; STS(11) = -g2;    // up (Jinv = I)
            STS(18) = xk0; STS(19) = xk1; STS(20) = xk2;   // xo
            STS(12) = 0.f; STS(13) = 0.f; STS(14) = 0.f;   // dx
            STS(15) = 0.f; STS(16) = 0.f; STS(17) = 0.f;   // dg
            STS(0) = 1.f; STS(1) = 0.f; STS(2) = 0.f;
            STS(3) = 0.f; STS(4) = 1.f; STS(5) = 0.f;
            STS(6) = 0.f; STS(7) = 0.f; STS(8) = 1.f;
        } else {
            float J00 = STS(0), J01 = STS(1), J02 = STS(2);
            float J10 = STS(3), J11 = STS(4), J12 = STS(5);
            float J20 = STS(6), J21 = STS(7), J22 = STS(8);
            const float dx0 = STS(12), dx1 = STS(13), dx2 = STS(14);
            float dg0 = STS(15), dg1 = STS(16), dg2 = STS(17);
            float nopt = STS(21);
            if (m3) {
                dg0 = g0 - gx0; dg1 = g1 - gx1; dg2 = g2 - gx2;
                gx0 += dg0; gx1 += dg1; gx2 += dg2;
                STS(15) = dg0; STS(16) = dg1; STS(17) = dg2;
            }
            const float gn = sqrtf(gx0 * gx0 + gx1 * gx1 + gx2 * gx2);
            const bool better = gn < nopt;
            if (better) {
                nopt = gn;
                STS(21) = gn;
                STS(18) = xk0; STS(19) = xk1; STS(20) = xk2;
            }
            mask = (nopt > 1e-5f) && (gn < 1.0f) && (m < M);

            const float v0 = dx0 * J00 + dx1 * J10 + dx2 * J20;
            const float v1 = dx0 * J01 + dx1 * J11 + dx2 * J21;
            const float v2 = dx0 * J02 + dx1 * J12 + dx2 * J22;
            const float Jd0 = J00 * dg0 + J01 * dg1 + J02 * dg2;
            const float Jd1 = J10 * dg0 + J11 * dg1 + J12 * dg2;
            const float Jd2 = J20 * dg0 + J21 * dg1 + J22 * dg2;
            const float a0 = dx0 - Jd0, a1 = dx1 - Jd1, a2 = dx2 - Jd2;
            float bden = v0 * dg0 + v1 * dg1 + v2 * dg2;
            bden += (bden >= 0.f) ? 1e-6f : -1e-6f;
            if (mask) {
                const float q0 = a0 / bden, q1 = a1 / bden, q2 = a2 / bden;
                J00 = fmaf(q0, v0, J00); J01 = fmaf(q0, v1, J01); J02 = fmaf(q0, v2, J02);
                J10 = fmaf(q1, v0, J10); J11 = fmaf(q1, v1, J11); J12 = fmaf(q1, v2, J12);
                J20 = fmaf(q2, v0, J20); J21 = fmaf(q2, v1, J21); J22 = fmaf(q2, v2, J22);
                STS(0) = J00; STS(1) = J01; STS(2) = J02;
                STS(3) = J10; STS(4) = J11; STS(5) = J12;
                STS(6) = J20; STS(7) = J21; STS(8) = J22;
            }
            if (m3) {
                STS(9) = -(J00 * gx0 + J01 * gx1 + J02 * gx2);
                STS(10) = -(J10 * gx0 + J11 * gx1 + J12 * gx2);
                STS(11) = -(J20 * gx0 + J21 * gx1 + J22 * gx2);
            }
        }
        ++step;
    }
#undef STS
}

extern "C" void kernel_launch(void* const* d_in, const int* in_sizes, int n_in,
                              void* d_out, int out_size, void* d_ws, size_t ws_size,
                              hipStream_t stream) {
    const float* x = (const float*)d_in[0];
    const float* bone_pts = (const float*)d_in[1];
    const float* transforms = (const float*)d_in[2];
    const float* delta_tf = (const float*)d_in[3];
    const float* W0 = (const float*)d_in[4];
    const float* b0 = (const float*)d_in[5];
    const float* W1 = (const float*)d_in[6];
    const float* b1 = (const float*)d_in[7];
    const float* W2 = (const float*)d_in[8];
    const float* b2 = (const float*)d_in[9];
    const float* W3 = (const float*)d_in[10];
    const float* b3 = (const float*)d_in[11];
    const float* W4 = (const float*)d_in[12];
    const float* b4 = (const float*)d_in[13];
    float* out = (float*)d_out;

    float* W0p = (float*)d_ws;    // 32*128
    float* W4p = W0p + 32 * 128;  // 128*32
    float* b4p = W4p + 128 * 32;  // 32

    prep_kernel<<<16, 256, 0, stream>>>(W0, W4, b4, W0p, W4p, b4p);

    const int Npts = in_sizes[0] / 3;
    const int M = Npts * 6;
    const int blocks = (M + PPB - 1) / PPB;
    snarf_kernel<<<blocks, BLOCK, 0, stream>>>(
        x, bone_pts, transforms, delta_tf, W0p, b0, W1, b1, W2, b2, W3, b3,
        W4p, b4p, out, Npts);
}